// Round 4
// baseline (3647.173 us; speedup 1.0000x reference)
//
#include <hip/hip_runtime.h>
#include <cstdint>
#include <cstddef>

#define B_ 4
#define N_ 4096
#define D_ 1024
#define CAND 16
#define M_ (B_*N_)
#define MD_ ((size_t)M_ * D_)

typedef __attribute__((ext_vector_type(8))) short short8;
typedef __attribute__((ext_vector_type(4))) float floatx4;

// ---------------------------------------------------------------------------
// Static device-global scratch (~422 MiB). Harness d_ws proved tiny (<1 MiB).
// Every buffer is fully overwritten before first read on every call.
// ---------------------------------------------------------------------------
__device__ __align__(16) double         g_Qd[MD_];            // 128 MiB exact q
__device__ __align__(16) double         g_Kd[MD_];            // 128 MiB exact k
__device__ __align__(16) unsigned short g_Qb[MD_];            // 32 MiB bf16 q
__device__ __align__(16) unsigned short g_Kb[MD_];            // 32 MiB bf16 k
__device__ __align__(16) float          g_Vf[MD_];            // 64 MiB fp32 v
__device__ __align__(16) unsigned short g_AO[MD_];            // 32 MiB bf16 attn-out
__device__ __align__(16) unsigned short g_WvT[(size_t)D_ * D_];  // 2 MiB bf16
__device__ __align__(16) unsigned short g_WoT[(size_t)D_ * D_];  // 2 MiB bf16
__device__ __align__(16) int            g_cand[(size_t)M_ * CAND];
__device__ __align__(16) int            g_t8i[(size_t)M_ * 8];
__device__ __align__(16) float          g_t8w[(size_t)M_ * 8];
__device__ unsigned int                 g_flag;

__device__ __forceinline__ float b2f(unsigned short u){
  return __uint_as_float(((unsigned int)u) << 16);
}
__device__ __forceinline__ unsigned short f2b(float f){
  unsigned int b = __float_as_uint(f);
  b += 0x7fffu + ((b >> 16) & 1u);   // RNE
  return (unsigned short)(b >> 16);
}
__device__ __forceinline__ bool finf(float f){  // finite check (exp != 0xFF)
  return ((__float_as_uint(f) >> 23) & 0xFFu) != 0xFFu;
}
__device__ __forceinline__ bool find(double d){
  return (d == d) && (d < 1.0e300) && (d > -1.0e300);
}

// ---------------------------------------------------------------------------
// Diagnostics: if any NaN/garbage in intermediates, stamp d_out[0] with
// 100*(1+flags) so the failing absmax decodes the broken stage.
// ---------------------------------------------------------------------------
__global__ void diag_reset(){ g_flag = 0u; }

__global__ __launch_bounds__(256)
void nan_probe(const float* __restrict__ out){
  size_t t = (size_t)blockIdx.x * 256 + threadIdx.x;
  unsigned f = 0;
  if (t < MD_){
    if (!finf(out[t]))  f |= 1u;
    if (!find(g_Qd[t])) f |= 2u;
    if (!find(g_Kd[t])) f |= 2u;
    if (!finf(g_Vf[t])) f |= 4u;
  }
  if (t < (size_t)M_ * 8){
    if (!finf(g_t8w[t])) f |= 8u;
    int ji = g_t8i[t];
    if (ji < -1 || ji >= N_) f |= 16u;
  }
  if (f) atomicOr(&g_flag, f);
}

__global__ void diag_stamp(float* __restrict__ out){
  if (g_flag) out[0] = 100.0f * (float)(1u + g_flag);
}

// ---------------------------------------------------------------------------
// Transpose Wv, Wo (fp32 [k][n] -> bf16 [n][k]) for B^T-layout bf16 GEMM
// ---------------------------------------------------------------------------
__global__ __launch_bounds__(256)
void transpose2(const float* __restrict__ Wv, const float* __restrict__ Wo){
  __shared__ float tile[32][33];
  const float* src = blockIdx.z ? Wo : Wv;
  unsigned short* dst = blockIdx.z ? g_WoT : g_WvT;
  int tx = threadIdx.x, ty = threadIdx.y;
  int n0 = blockIdx.x * 32, k0 = blockIdx.y * 32;
  for (int r = ty; r < 32; r += 8) tile[r][tx] = src[(size_t)(k0 + r) * D_ + n0 + tx];
  __syncthreads();
  for (int r = ty; r < 32; r += 8) dst[(size_t)(n0 + r) * D_ + k0 + tx] = f2b(tile[tx][r]);
}

// ---------------------------------------------------------------------------
// Exact projection GEMM: out = X @ W + bias, X/W fp32. fp32 products are
// exact in fp64; fp64 accumulation -> matches high-precision ref to ~1e-13.
// Stores fp64 (rescore path) + bf16 (approx-score path).
// Block 256 thr (16x16), tile 64x128, BK=16, thread tile 4x8.
// which==0 -> Q buffers, which==1 -> K buffers.
// ---------------------------------------------------------------------------
__global__ __launch_bounds__(256)
void qk_f64_gemm(const float* __restrict__ X, const float* __restrict__ W,
                 const float* __restrict__ bias, int which){
  double* __restrict__ outd = which ? g_Kd : g_Qd;
  unsigned short* __restrict__ outb = which ? g_Kb : g_Qb;
  __shared__ float As[16][64];    // [k][m]
  __shared__ float Bs[16][128];   // [k][n]
  int tid = threadIdx.x;
  int tx = tid & 15, ty = tid >> 4;
  size_t m0 = (size_t)blockIdx.x * 64;
  int n0 = blockIdx.y * 128;
  double acc[4][8];
  #pragma unroll
  for (int u = 0; u < 4; u++)
    #pragma unroll
    for (int v = 0; v < 8; v++) acc[u][v] = 0.0;

  int arow = tid >> 2, acg = (tid & 3) * 4;    // X: 64 rows x 16 cols
  int brow = tid >> 4, bcg = (tid & 15) * 8;   // W: 16 rows x 128 cols

  for (int k0 = 0; k0 < D_; k0 += 16){
    float4 xv = *(const float4*)&X[(m0 + arow) * D_ + k0 + acg];
    As[acg + 0][arow] = xv.x;
    As[acg + 1][arow] = xv.y;
    As[acg + 2][arow] = xv.z;
    As[acg + 3][arow] = xv.w;
    const float* wp = &W[(size_t)(k0 + brow) * D_ + n0 + bcg];
    float4 w0 = *(const float4*)wp;
    float4 w1 = *(const float4*)(wp + 4);
    Bs[brow][bcg + 0] = w0.x; Bs[brow][bcg + 1] = w0.y;
    Bs[brow][bcg + 2] = w0.z; Bs[brow][bcg + 3] = w0.w;
    Bs[brow][bcg + 4] = w1.x; Bs[brow][bcg + 5] = w1.y;
    Bs[brow][bcg + 6] = w1.z; Bs[brow][bcg + 7] = w1.w;
    __syncthreads();
    #pragma unroll
    for (int kk = 0; kk < 16; kk++){
      double a[4], bb[8];
      #pragma unroll
      for (int u = 0; u < 4; u++) a[u] = (double)As[kk][ty + 16 * u];
      #pragma unroll
      for (int v = 0; v < 8; v++) bb[v] = (double)Bs[kk][tx + 16 * v];
      #pragma unroll
      for (int u = 0; u < 4; u++)
        #pragma unroll
        for (int v = 0; v < 8; v++) acc[u][v] = fma(a[u], bb[v], acc[u][v]);
    }
    __syncthreads();
  }
  #pragma unroll
  for (int u = 0; u < 4; u++){
    size_t i = m0 + ty + 16 * u;
    #pragma unroll
    for (int v = 0; v < 8; v++){
      int j = n0 + tx + 16 * v;
      double val = acc[u][v] + (double)bias[j];
      outd[i * D_ + j] = val;
      outb[i * D_ + j] = f2b((float)val);
    }
  }
}

// ---------------------------------------------------------------------------
// bf16 MFMA GEMM (m93-style): C = A @ Bt^T + bias, fp32 out.
// Block 256 thr = 4 waves (2x2), tile 128x128, wave 64x64, 16x16x32 MFMA.
// sel==0: A=Af32 (fp32 -> bf16 on stage), Bt=g_WvT, C=g_Vf   (V projection)
// sel==1: A=g_AO (bf16),                  Bt=g_WoT, C=Cout   (O projection)
// ---------------------------------------------------------------------------
__global__ __launch_bounds__(256)
void gemm_bf16(const float* __restrict__ Af32, const float* __restrict__ bias,
               float* __restrict__ Cout, int sel){
  const unsigned short* Bt = sel ? g_WoT : g_WvT;
  float* C = sel ? Cout : g_Vf;
  __shared__ unsigned short __align__(16) As[128 * 32];
  __shared__ unsigned short __align__(16) Bs[128 * 32];
  int tid = threadIdx.x;
  size_t m0 = (size_t)blockIdx.x * 128;
  int n0 = blockIdx.y * 128;
  int l = tid & 63, wid = tid >> 6;
  int wm = (wid >> 1) * 64, wn = (wid & 1) * 64;
  int quad = l >> 4, lr = l & 15;
  int srow = tid >> 2, scol = (tid & 3) * 8;
  floatx4 acc[4][4];
  #pragma unroll
  for (int i = 0; i < 4; i++)
    #pragma unroll
    for (int j = 0; j < 4; j++) acc[i][j] = (floatx4)0.0f;

  for (int k0 = 0; k0 < D_; k0 += 32){
    #pragma unroll
    for (int it = 0; it < 2; it++){
      int r = srow + it * 64;
      if (sel == 0){
        float4 f0 = *(const float4*)&Af32[(m0 + r) * D_ + k0 + scol];
        float4 f1 = *(const float4*)&Af32[(m0 + r) * D_ + k0 + scol + 4];
        ushort4 u0, u1;
        u0.x = f2b(f0.x); u0.y = f2b(f0.y); u0.z = f2b(f0.z); u0.w = f2b(f0.w);
        u1.x = f2b(f1.x); u1.y = f2b(f1.y); u1.z = f2b(f1.z); u1.w = f2b(f1.w);
        *(ushort4*)&As[r * 32 + scol] = u0;
        *(ushort4*)&As[r * 32 + scol + 4] = u1;
      } else {
        *(uint4*)&As[r * 32 + scol] = *(const uint4*)&g_AO[(m0 + r) * D_ + k0 + scol];
      }
      *(uint4*)&Bs[r * 32 + scol] = *(const uint4*)&Bt[(size_t)(n0 + r) * D_ + k0 + scol];
    }
    __syncthreads();
    short8 af[4], bf[4];
    #pragma unroll
    for (int i = 0; i < 4; i++) af[i] = *(short8*)&As[(wm + i * 16 + lr) * 32 + quad * 8];
    #pragma unroll
    for (int j = 0; j < 4; j++) bf[j] = *(short8*)&Bs[(wn + j * 16 + lr) * 32 + quad * 8];
    #pragma unroll
    for (int i = 0; i < 4; i++)
      #pragma unroll
      for (int j = 0; j < 4; j++)
        acc[i][j] = __builtin_amdgcn_mfma_f32_16x16x32_bf16(af[i], bf[j], acc[i][j], 0, 0, 0);
    __syncthreads();
  }
  // C/D layout (m89-verified): col = lane&15, row = quad*4 + reg
  #pragma unroll
  for (int i = 0; i < 4; i++)
    #pragma unroll
    for (int j = 0; j < 4; j++)
      #pragma unroll
      for (int rg = 0; rg < 4; rg++){
        size_t row = m0 + wm + i * 16 + quad * 4 + rg;
        int col = n0 + wn + j * 16 + lr;
        C[row * D_ + col] = acc[i][j][rg] + bias[col];
      }
}

// ---------------------------------------------------------------------------
// Top-16 candidate maintenance (registers, fully unrolled)
// ---------------------------------------------------------------------------
__device__ __forceinline__ void topc_insert(float (&cv)[CAND], int (&ci)[CAND],
                                            float &vmin, int &pmin, float v, int j){
  #pragma unroll
  for (int u = 0; u < CAND; u++) if (u == pmin){ cv[u] = v; ci[u] = j; }
  float m = cv[0]; int p = 0;
  #pragma unroll
  for (int u = 1; u < CAND; u++) if (cv[u] < m){ m = cv[u]; p = u; }
  vmin = m; pmin = p;
}

// ---------------------------------------------------------------------------
// Approximate causal scores (bf16 MFMA) fused with per-row top-16 candidate
// selection. Block tile 64 q-rows x 128 k-cols, 4 waves (2x2 of 32x64).
// bf16 score error (~2e-3) vs rank-8..16 margin (~0.08) => true top-8
// contained in candidates w.p. ~1.
// ---------------------------------------------------------------------------
__global__ __launch_bounds__(256)
void scores_topc(){
  __shared__ unsigned short __align__(16) Qs[64 * 32];
  __shared__ unsigned short __align__(16) Ks[128 * 32];
  __shared__ float __align__(16) Sc[64 * 129];
  int tid = threadIdx.x;
  int iblk = blockIdx.x, b = blockIdx.y;
  size_t rowbase = (size_t)b * N_ + iblk * 64;
  int l = tid & 63, wid = tid >> 6;
  int wm = (wid >> 1) * 32, wn = (wid & 1) * 64;
  int quad = l >> 4, lr = l & 15;
  int srow = tid >> 2, scol = (tid & 3) * 8;
  int r = tid >> 2, quarter = tid & 3;
  int irow = iblk * 64 + r;

  float cv[CAND]; int ci[CAND];
  #pragma unroll
  for (int u = 0; u < CAND; u++){ cv[u] = -3.0e38f; ci[u] = -1; }
  float vmin = -3.0e38f; int pmin = 0;

  int jmax = (iblk * 64 + 63) >> 7;
  for (int jblk = 0; jblk <= jmax; jblk++){
    floatx4 acc[2][4];
    #pragma unroll
    for (int i = 0; i < 2; i++)
      #pragma unroll
      for (int j = 0; j < 4; j++) acc[i][j] = (floatx4)0.0f;
    for (int k0 = 0; k0 < D_; k0 += 32){
      *(uint4*)&Qs[srow * 32 + scol] = *(const uint4*)&g_Qb[(rowbase + srow) * D_ + k0 + scol];
      #pragma unroll
      for (int it = 0; it < 2; it++){
        int rr = srow + it * 64;
        *(uint4*)&Ks[rr * 32 + scol] =
            *(const uint4*)&g_Kb[((size_t)b * N_ + jblk * 128 + rr) * D_ + k0 + scol];
      }
      __syncthreads();
      short8 af[2], bq[4];
      #pragma unroll
      for (int i = 0; i < 2; i++) af[i] = *(short8*)&Qs[(wm + i * 16 + lr) * 32 + quad * 8];
      #pragma unroll
      for (int j = 0; j < 4; j++) bq[j] = *(short8*)&Ks[(wn + j * 16 + lr) * 32 + quad * 8];
      #pragma unroll
      for (int i = 0; i < 2; i++)
        #pragma unroll
        for (int j = 0; j < 4; j++)
          acc[i][j] = __builtin_amdgcn_mfma_f32_16x16x32_bf16(af[i], bq[j], acc[i][j], 0, 0, 0);
      __syncthreads();
    }
    #pragma unroll
    for (int i = 0; i < 2; i++)
      #pragma unroll
      for (int j = 0; j < 4; j++)
        #pragma unroll
        for (int rg = 0; rg < 4; rg++)
          Sc[(wm + i * 16 + quad * 4 + rg) * 129 + wn + j * 16 + lr] = acc[i][j][rg] * 0.03125f;
    __syncthreads();
    int jbase = jblk * 128 + quarter * 32;
    for (int c = 0; c < 32; c++){
      float v = Sc[r * 129 + quarter * 32 + c];
      int j = jbase + c;
      if (j <= irow && v > vmin) topc_insert(cv, ci, vmin, pmin, v, j);
    }
    __syncthreads();
  }
  // merge 4 per-row partial lists via LDS (reuse Sc: 4096 floats + 4096 ints)
  float* mv = Sc;
  int* mi = (int*)&Sc[4096];
  #pragma unroll
  for (int u = 0; u < CAND; u++){ mv[tid * CAND + u] = cv[u]; mi[tid * CAND + u] = ci[u]; }
  __syncthreads();
  if (quarter == 0){
    for (int p = 1; p < 4; p++)
      #pragma unroll
      for (int u = 0; u < CAND; u++){
        float v = mv[(tid + p) * CAND + u]; int j = mi[(tid + p) * CAND + u];
        if (j >= 0 && v > vmin) topc_insert(cv, ci, vmin, pmin, v, j);
      }
    size_t gi = rowbase + r;
    #pragma unroll
    for (int u = 0; u < CAND; u++) g_cand[gi * CAND + u] = ci[u];
  }
}

// ---------------------------------------------------------------------------
// fp64 rescore of 16 candidates/row -> exact top-8 + softmax weights.
// One 256-thr block per row; wave w handles candidates 4w..4w+3.
// ---------------------------------------------------------------------------
__global__ __launch_bounds__(256)
void rescore_top8(){
  int i = blockIdx.x;
  int b = i >> 12;
  int tid = threadIdx.x, l = tid & 63, w = tid >> 6;
  __shared__ double cs[CAND];
  __shared__ int cid[CAND];
  if (tid < CAND) cid[tid] = g_cand[(size_t)i * CAND + tid];
  __syncthreads();
  double q[16];
  #pragma unroll
  for (int u = 0; u < 16; u++) q[u] = g_Qd[(size_t)i * D_ + l + 64 * u];
  for (int c = w * 4; c < w * 4 + 4; c++){
    int j = cid[c];
    double s = 0.0;
    if (j >= 0){
      size_t ko = ((size_t)(b * N_ + j)) * D_;
      #pragma unroll
      for (int u = 0; u < 16; u++) s = fma(q[u], g_Kd[ko + l + 64 * u], s);
    }
    #pragma unroll
    for (int off = 32; off >= 1; off >>= 1) s += __shfl_down(s, off);
    if (l == 0) cs[c] = (j >= 0) ? s * 0.03125 : -1.0e300;
  }
  __syncthreads();
  if (tid == 0){
    double v8[8]; int i8[8];
    bool used[CAND];
    for (int u = 0; u < CAND; u++) used[u] = false;
    for (int rk = 0; rk < 8; rk++){
      double best = -1.0e300; int bp = -1;
      for (int c = 0; c < CAND; c++)
        if (!used[c] && cid[c] >= 0 && cs[c] > best){ best = cs[c]; bp = c; }
      if (bp >= 0){ used[bp] = true; v8[rk] = best; i8[rk] = cid[bp]; }
      else { v8[rk] = -1.0e300; i8[rk] = -1; }
    }
    if (i8[0] < 0){ i8[0] = i & (N_ - 1); v8[0] = 0.0; }   // never expected
    double mx = v8[0];
    double e[8]; double Z = 0.0;
    for (int rk = 0; rk < 8; rk++){
      e[rk] = (i8[rk] >= 0) ? exp(v8[rk] - mx) : 0.0;
      Z += e[rk];
    }
    for (int rk = 0; rk < 8; rk++){
      g_t8i[(size_t)i * 8 + rk] = i8[rk];
      g_t8w[(size_t)i * 8 + rk] = (float)(e[rk] / Z);
    }
  }
}

// ---------------------------------------------------------------------------
// attn_out[i] = sum_r w_r * v[idx_r]  (fp32 accumulate, bf16 out for O-GEMM)
// ---------------------------------------------------------------------------
__global__ __launch_bounds__(256)
void gather_v(){
  int i = blockIdx.x;
  int b = i >> 12;
  int tid = threadIdx.x;
  __shared__ float ws8[8];
  __shared__ int id8[8];
  if (tid < 8){ ws8[tid] = g_t8w[(size_t)i * 8 + tid]; id8[tid] = g_t8i[(size_t)i * 8 + tid]; }
  __syncthreads();
  int d0 = tid * 4;
  float a0 = 0.f, a1 = 0.f, a2 = 0.f, a3 = 0.f;
  #pragma unroll
  for (int rk = 0; rk < 8; rk++){
    int j = id8[rk];
    if (j < 0) continue;
    float wgt = ws8[rk];
    float4 vv = *(const float4*)&g_Vf[((size_t)(b * N_ + j)) * D_ + d0];
    a0 += wgt * vv.x; a1 += wgt * vv.y; a2 += wgt * vv.z; a3 += wgt * vv.w;
  }
  ushort4 o;
  o.x = f2b(a0); o.y = f2b(a1); o.z = f2b(a2); o.w = f2b(a3);
  *(ushort4*)&g_AO[(size_t)i * D_ + d0] = o;
}

// ---------------------------------------------------------------------------
extern "C" void kernel_launch(void* const* d_in, const int* in_sizes, int n_in,
                              void* d_out, int out_size, void* d_ws, size_t ws_size,
                              hipStream_t stream){
  const float* S  = (const float*)d_in[0];
  const float* Wq = (const float*)d_in[1];
  const float* bq = (const float*)d_in[2];
  const float* Wk = (const float*)d_in[3];
  const float* bk = (const float*)d_in[4];
  const float* Wv = (const float*)d_in[5];
  const float* bv = (const float*)d_in[6];
  const float* Wo = (const float*)d_in[7];
  const float* bo = (const float*)d_in[8];
  float* out = (float*)d_out;
  (void)d_ws; (void)ws_size; (void)in_sizes; (void)n_in; (void)out_size;

  diag_reset<<<1, 1, 0, stream>>>();
  transpose2<<<dim3(32, 32, 2), dim3(32, 8), 0, stream>>>(Wv, Wo);
  qk_f64_gemm<<<dim3(256, 8), 256, 0, stream>>>(S, Wq, bq, 0);
  qk_f64_gemm<<<dim3(256, 8), 256, 0, stream>>>(S, Wk, bk, 1);
  gemm_bf16<<<dim3(128, 8), 256, 0, stream>>>(S, bv, nullptr, 0);
  scores_topc<<<dim3(64, 4), 256, 0, stream>>>();
  rescore_top8<<<dim3(M_), 256, 0, stream>>>();
  gather_v<<<dim3(M_), 256, 0, stream>>>();
  gemm_bf16<<<dim3(128, 8), 256, 0, stream>>>(nullptr, bo, out, 1);
  nan_probe<<<dim3(65536), 256, 0, stream>>>(out);
  diag_stamp<<<1, 1, 0, stream>>>(out);
}

// Round 5
// 2807.166 us; speedup vs baseline: 1.2992x; 1.2992x over previous
//
#include <hip/hip_runtime.h>
#include <cstdint>
#include <cstddef>

#define B_ 4
#define N_ 4096
#define D_ 1024
#define CAND 16
#define M_ (B_*N_)
#define MD_ ((size_t)M_ * D_)

typedef __attribute__((ext_vector_type(8))) short short8;
typedef __attribute__((ext_vector_type(4))) float floatx4;

// ---------------------------------------------------------------------------
// Static device-global scratch (~677 MiB). d_ws proved tiny in rounds 1-2.
// Every buffer fully overwritten before first read on every call.
// ---------------------------------------------------------------------------
__device__ __align__(16) double         g_Qd[MD_];            // 128 MiB exact q
__device__ __align__(16) double         g_Kd[MD_];            // 128 MiB exact k
__device__ __align__(16) unsigned short g_Qb[MD_];            // 32 MiB bf16 q
__device__ __align__(16) unsigned short g_Kb[MD_];            // 32 MiB bf16 k
__device__ __align__(16) float          g_Vf[MD_];            // 64 MiB fp32 v
__device__ __align__(16) unsigned short g_AO[MD_];            // 32 MiB bf16 attn-out
__device__ __align__(16) unsigned short g_WvT[(size_t)D_ * D_];  // 2 MiB bf16
__device__ __align__(16) unsigned short g_WoT[(size_t)D_ * D_];  // 2 MiB bf16
__device__ __align__(16) float          g_S[(size_t)B_ * N_ * N_]; // 256 MiB scores
__device__ __align__(16) int            g_cand[(size_t)M_ * CAND];
__device__ __align__(16) int            g_t8i[(size_t)M_ * 8];
__device__ __align__(16) float          g_t8w[(size_t)M_ * 8];

__device__ __forceinline__ float b2f(unsigned short u){
  return __uint_as_float(((unsigned int)u) << 16);
}
__device__ __forceinline__ unsigned short f2b(float f){
  unsigned int b = __float_as_uint(f);
  b += 0x7fffu + ((b >> 16) & 1u);   // RNE
  return (unsigned short)(b >> 16);
}

// ---------------------------------------------------------------------------
// Transpose Wv, Wo (fp32 [k][n] -> bf16 [n][k]) for B^T-layout bf16 GEMM
// ---------------------------------------------------------------------------
__global__ __launch_bounds__(256)
void transpose2(const float* __restrict__ Wv, const float* __restrict__ Wo){
  __shared__ float tile[32][33];
  const float* src = blockIdx.z ? Wo : Wv;
  unsigned short* dst = blockIdx.z ? g_WoT : g_WvT;
  int tx = threadIdx.x, ty = threadIdx.y;
  int n0 = blockIdx.x * 32, k0 = blockIdx.y * 32;
  for (int r = ty; r < 32; r += 8) tile[r][tx] = src[(size_t)(k0 + r) * D_ + n0 + tx];
  __syncthreads();
  for (int r = ty; r < 32; r += 8) dst[(size_t)(n0 + r) * D_ + k0 + tx] = f2b(tile[tx][r]);
}

// ---------------------------------------------------------------------------
// Exact projection GEMM: out = X @ W + bias (X,W fp32; fp64 accumulate).
// fp64 staged in LDS so the hot loop is ds_read_b64 + v_fma_f64 only.
// Block 256 thr (16x16), tile 64x128, BK=16, thread tile 4x8.
// blockIdx.z==0 -> Q buffers, ==1 -> K buffers. Emits fp64 + bf16 copies.
// ---------------------------------------------------------------------------
__global__ __launch_bounds__(256)
void qk_f64_gemm(const float* __restrict__ X,
                 const float* __restrict__ Wq, const float* __restrict__ bq,
                 const float* __restrict__ Wk, const float* __restrict__ bk){
  int which = blockIdx.z;
  const float* __restrict__ W = which ? Wk : Wq;
  const float* __restrict__ bias = which ? bk : bq;
  double* __restrict__ outd = which ? g_Kd : g_Qd;
  unsigned short* __restrict__ outb = which ? g_Kb : g_Qb;
  __shared__ double Ad[16][64];    // [k][m]  8 KiB
  __shared__ double Bd[16][128];   // [k][n] 16 KiB
  int tid = threadIdx.x;
  int tx = tid & 15, ty = tid >> 4;
  size_t m0 = (size_t)blockIdx.x * 64;
  int n0 = blockIdx.y * 128;
  double acc[4][8];
  #pragma unroll
  for (int u = 0; u < 4; u++)
    #pragma unroll
    for (int v = 0; v < 8; v++) acc[u][v] = 0.0;

  int arow = tid >> 2, acg = (tid & 3) * 4;    // X: 64 rows x 16 cols
  int brow = tid >> 4, bcg = (tid & 15) * 8;   // W: 16 rows x 128 cols

  for (int k0 = 0; k0 < D_; k0 += 16){
    float4 xv = *(const float4*)&X[(m0 + arow) * D_ + k0 + acg];
    Ad[acg + 0][arow] = (double)xv.x;
    Ad[acg + 1][arow] = (double)xv.y;
    Ad[acg + 2][arow] = (double)xv.z;
    Ad[acg + 3][arow] = (double)xv.w;
    const float* wp = &W[(size_t)(k0 + brow) * D_ + n0 + bcg];
    float4 w0 = *(const float4*)wp;
    float4 w1 = *(const float4*)(wp + 4);
    Bd[brow][bcg + 0] = (double)w0.x; Bd[brow][bcg + 1] = (double)w0.y;
    Bd[brow][bcg + 2] = (double)w0.z; Bd[brow][bcg + 3] = (double)w0.w;
    Bd[brow][bcg + 4] = (double)w1.x; Bd[brow][bcg + 5] = (double)w1.y;
    Bd[brow][bcg + 6] = (double)w1.z; Bd[brow][bcg + 7] = (double)w1.w;
    __syncthreads();
    #pragma unroll
    for (int kk = 0; kk < 16; kk++){
      double a[4], bb[8];
      #pragma unroll
      for (int u = 0; u < 4; u++) a[u] = Ad[kk][ty + 16 * u];
      #pragma unroll
      for (int v = 0; v < 8; v++) bb[v] = Bd[kk][tx + 16 * v];
      #pragma unroll
      for (int u = 0; u < 4; u++)
        #pragma unroll
        for (int v = 0; v < 8; v++) acc[u][v] = fma(a[u], bb[v], acc[u][v]);
    }
    __syncthreads();
  }
  #pragma unroll
  for (int u = 0; u < 4; u++){
    size_t i = m0 + ty + 16 * u;
    #pragma unroll
    for (int v = 0; v < 8; v++){
      int j = n0 + tx + 16 * v;
      double val = acc[u][v] + (double)bias[j];
      outd[i * D_ + j] = val;
      outb[i * D_ + j] = f2b((float)val);
    }
  }
}

// ---------------------------------------------------------------------------
// bf16 MFMA GEMM (m93-style): C = A @ Bt^T + bias, fp32 out.
// Block 256 thr = 4 waves (2x2), tile 128x128, wave 64x64, 16x16x32 MFMA.
// sel==0: A=Af32 (fp32 -> bf16 on stage), Bt=g_WvT, C=g_Vf   (V projection)
// sel==1: A=g_AO (bf16),                  Bt=g_WoT, C=Cout   (O projection)
// ---------------------------------------------------------------------------
__global__ __launch_bounds__(256)
void gemm_bf16(const float* __restrict__ Af32, const float* __restrict__ bias,
               float* __restrict__ Cout, int sel){
  const unsigned short* Bt = sel ? g_WoT : g_WvT;
  float* C = sel ? Cout : g_Vf;
  __shared__ unsigned short __align__(16) As[128 * 32];
  __shared__ unsigned short __align__(16) Bs[128 * 32];
  int tid = threadIdx.x;
  size_t m0 = (size_t)blockIdx.x * 128;
  int n0 = blockIdx.y * 128;
  int l = tid & 63, wid = tid >> 6;
  int wm = (wid >> 1) * 64, wn = (wid & 1) * 64;
  int quad = l >> 4, lr = l & 15;
  int srow = tid >> 2, scol = (tid & 3) * 8;
  floatx4 acc[4][4];
  #pragma unroll
  for (int i = 0; i < 4; i++)
    #pragma unroll
    for (int j = 0; j < 4; j++) acc[i][j] = (floatx4)0.0f;

  for (int k0 = 0; k0 < D_; k0 += 32){
    #pragma unroll
    for (int it = 0; it < 2; it++){
      int r = srow + it * 64;
      if (sel == 0){
        float4 f0 = *(const float4*)&Af32[(m0 + r) * D_ + k0 + scol];
        float4 f1 = *(const float4*)&Af32[(m0 + r) * D_ + k0 + scol + 4];
        ushort4 u0, u1;
        u0.x = f2b(f0.x); u0.y = f2b(f0.y); u0.z = f2b(f0.z); u0.w = f2b(f0.w);
        u1.x = f2b(f1.x); u1.y = f2b(f1.y); u1.z = f2b(f1.z); u1.w = f2b(f1.w);
        *(ushort4*)&As[r * 32 + scol] = u0;
        *(ushort4*)&As[r * 32 + scol + 4] = u1;
      } else {
        *(uint4*)&As[r * 32 + scol] = *(const uint4*)&g_AO[(m0 + r) * D_ + k0 + scol];
      }
      *(uint4*)&Bs[r * 32 + scol] = *(const uint4*)&Bt[(size_t)(n0 + r) * D_ + k0 + scol];
    }
    __syncthreads();
    short8 af[4], bf[4];
    #pragma unroll
    for (int i = 0; i < 4; i++) af[i] = *(short8*)&As[(wm + i * 16 + lr) * 32 + quad * 8];
    #pragma unroll
    for (int j = 0; j < 4; j++) bf[j] = *(short8*)&Bs[(wn + j * 16 + lr) * 32 + quad * 8];
    #pragma unroll
    for (int i = 0; i < 4; i++)
      #pragma unroll
      for (int j = 0; j < 4; j++)
        acc[i][j] = __builtin_amdgcn_mfma_f32_16x16x32_bf16(af[i], bf[j], acc[i][j], 0, 0, 0);
    __syncthreads();
  }
  // C/D layout (m89-verified): col = lane&15, row = quad*4 + reg
  #pragma unroll
  for (int i = 0; i < 4; i++)
    #pragma unroll
    for (int j = 0; j < 4; j++)
      #pragma unroll
      for (int rg = 0; rg < 4; rg++){
        size_t row = m0 + wm + i * 16 + quad * 4 + rg;
        int col = n0 + wn + j * 16 + lr;
        C[row * D_ + col] = acc[i][j][rg] + bias[col];
      }
}

// ---------------------------------------------------------------------------
// Causal score tiles: S[b][i][j] = (q_i . k_j)/32, fp32, 128x128 tiles.
// Same MFMA structure as gemm_bf16; A = g_Qb rows, Bt = g_Kb rows.
// Grid (32, 32, 4) = (jt, it, b); jt > it exits early (uniform real blocks).
// Diagonal tiles mask j > i to -3e38. Tiles with jt > it are never read.
// ---------------------------------------------------------------------------
__global__ __launch_bounds__(256)
void scores_gemm(){
  int jt = blockIdx.x, it = blockIdx.y, b = blockIdx.z;
  if (jt > it) return;
  __shared__ unsigned short __align__(16) As[128 * 32];
  __shared__ unsigned short __align__(16) Bs[128 * 32];
  int tid = threadIdx.x;
  size_t am0 = (size_t)b * N_ + it * 128;   // Q rows (global)
  size_t bn0 = (size_t)b * N_ + jt * 128;   // K rows (global)
  int l = tid & 63, wid = tid >> 6;
  int wm = (wid >> 1) * 64, wn = (wid & 1) * 64;
  int quad = l >> 4, lr = l & 15;
  int srow = tid >> 2, scol = (tid & 3) * 8;
  floatx4 acc[4][4];
  #pragma unroll
  for (int i = 0; i < 4; i++)
    #pragma unroll
    for (int j = 0; j < 4; j++) acc[i][j] = (floatx4)0.0f;

  for (int k0 = 0; k0 < D_; k0 += 32){
    #pragma unroll
    for (int it2 = 0; it2 < 2; it2++){
      int r = srow + it2 * 64;
      *(uint4*)&As[r * 32 + scol] = *(const uint4*)&g_Qb[(am0 + r) * D_ + k0 + scol];
      *(uint4*)&Bs[r * 32 + scol] = *(const uint4*)&g_Kb[(bn0 + r) * D_ + k0 + scol];
    }
    __syncthreads();
    short8 af[4], bf[4];
    #pragma unroll
    for (int i = 0; i < 4; i++) af[i] = *(short8*)&As[(wm + i * 16 + lr) * 32 + quad * 8];
    #pragma unroll
    for (int j = 0; j < 4; j++) bf[j] = *(short8*)&Bs[(wn + j * 16 + lr) * 32 + quad * 8];
    #pragma unroll
    for (int i = 0; i < 4; i++)
      #pragma unroll
      for (int j = 0; j < 4; j++)
        acc[i][j] = __builtin_amdgcn_mfma_f32_16x16x32_bf16(af[i], bf[j], acc[i][j], 0, 0, 0);
    __syncthreads();
  }
  #pragma unroll
  for (int i = 0; i < 4; i++)
    #pragma unroll
    for (int j = 0; j < 4; j++)
      #pragma unroll
      for (int rg = 0; rg < 4; rg++){
        int row = it * 128 + wm + i * 16 + quad * 4 + rg;   // in-batch
        int col = jt * 128 + wn + j * 16 + lr;
        float v = acc[i][j][rg] * 0.03125f;
        if (col > row) v = -3.0e38f;
        g_S[((size_t)b * N_ + row) * N_ + col] = v;
      }
}

// ---------------------------------------------------------------------------
// Per-row top-16 of causal scores. One wave per row (4 rows/block).
// Per-lane top-16 kept in u-major LDS (conflict-free: lane-adjacent addrs),
// then 16 rounds of wave argmax butterfly with deterministic tie-break.
// ---------------------------------------------------------------------------
__global__ __launch_bounds__(256)
void row_topk(){
  __shared__ float lv[CAND * 256];   // [u][wave*64+lane]
  __shared__ int   li[CAND * 256];
  int w = threadIdx.x >> 6, l = threadIdx.x & 63;
  int g = threadIdx.x;                      // w*64 + l
  int i = blockIdx.x * 4 + w;               // global row
  int irow = i & (N_ - 1);                  // in-batch row
  const float* Srow = &g_S[(size_t)i * N_];
  #pragma unroll
  for (int u = 0; u < CAND; u++){ lv[u * 256 + g] = -3.0e38f; li[u * 256 + g] = -1; }
  float vmin = -3.0e38f; int pmin = 0;
  for (int j = l; j <= irow; j += 64){
    float v = Srow[j];
    if (v > vmin){
      lv[pmin * 256 + g] = v; li[pmin * 256 + g] = j;
      float m = lv[g]; int p = 0;
      #pragma unroll
      for (int u = 1; u < CAND; u++){ float x = lv[u * 256 + g]; if (x < m){ m = x; p = u; } }
      vmin = m; pmin = p;
    }
  }
  // per-lane running max
  float mv = lv[g]; int mp = 0;
  #pragma unroll
  for (int u = 1; u < CAND; u++){ float x = lv[u * 256 + g]; if (x > mv){ mv = x; mp = u; } }
  int mj = li[mp * 256 + g];
  // 16 rounds of cross-lane argmax (total order: value desc, lane asc)
  for (int rd = 0; rd < CAND; rd++){
    float bv = mv; int bj = mj; int bl = l;
    #pragma unroll
    for (int off = 32; off >= 1; off >>= 1){
      float ov = __shfl_xor(bv, off);
      int oj = __shfl_xor(bj, off);
      int ol = __shfl_xor(bl, off);
      if (ov > bv || (ov == bv && ol < bl)){ bv = ov; bj = oj; bl = ol; }
    }
    bool valid = (bv > -2.9e38f);
    if (l == 0) g_cand[(size_t)i * CAND + rd] = valid ? bj : -1;
    if (valid && bl == l){
      lv[mp * 256 + g] = -3.0e38f;
      mv = lv[g]; mp = 0;
      #pragma unroll
      for (int u = 1; u < CAND; u++){ float x = lv[u * 256 + g]; if (x > mv){ mv = x; mp = u; } }
      mj = li[mp * 256 + g];
    }
  }
}

// ---------------------------------------------------------------------------
// fp64 rescore of 16 candidates/row -> exact top-8 + softmax weights.
// One 256-thr block per row; wave w handles candidates 4w..4w+3.
// ---------------------------------------------------------------------------
__global__ __launch_bounds__(256)
void rescore_top8(){
  int i = blockIdx.x;
  int b = i >> 12;
  int tid = threadIdx.x, l = tid & 63, w = tid >> 6;
  __shared__ double cs[CAND];
  __shared__ int cid[CAND];
  if (tid < CAND) cid[tid] = g_cand[(size_t)i * CAND + tid];
  __syncthreads();
  double q[16];
  #pragma unroll
  for (int u = 0; u < 16; u++) q[u] = g_Qd[(size_t)i * D_ + l + 64 * u];
  for (int c = w * 4; c < w * 4 + 4; c++){
    int j = cid[c];
    double s = 0.0;
    if (j >= 0){
      size_t ko = ((size_t)(b * N_ + j)) * D_;
      #pragma unroll
      for (int u = 0; u < 16; u++) s = fma(q[u], g_Kd[ko + l + 64 * u], s);
    }
    #pragma unroll
    for (int off = 32; off >= 1; off >>= 1) s += __shfl_down(s, off);
    if (l == 0) cs[c] = (j >= 0) ? s * 0.03125 : -1.0e300;
  }
  __syncthreads();
  if (tid == 0){
    double v8[8]; int i8[8];
    bool used[CAND];
    for (int u = 0; u < CAND; u++) used[u] = false;
    for (int rk = 0; rk < 8; rk++){
      double best = -1.0e300; int bp = -1;
      for (int c = 0; c < CAND; c++)
        if (!used[c] && cid[c] >= 0 && cs[c] > best){ best = cs[c]; bp = c; }
      if (bp >= 0){ used[bp] = true; v8[rk] = best; i8[rk] = cid[bp]; }
      else { v8[rk] = -1.0e300; i8[rk] = -1; }
    }
    if (i8[0] < 0){ i8[0] = i & (N_ - 1); v8[0] = 0.0; }   // never expected
    double mx = v8[0];
    double e[8]; double Z = 0.0;
    for (int rk = 0; rk < 8; rk++){
      e[rk] = (i8[rk] >= 0) ? exp(v8[rk] - mx) : 0.0;
      Z += e[rk];
    }
    for (int rk = 0; rk < 8; rk++){
      g_t8i[(size_t)i * 8 + rk] = i8[rk];
      g_t8w[(size_t)i * 8 + rk] = (float)(e[rk] / Z);
    }
  }
}

// ---------------------------------------------------------------------------
// attn_out[i] = sum_r w_r * v[idx_r]  (fp32 accumulate, bf16 out for O-GEMM)
// ---------------------------------------------------------------------------
__global__ __launch_bounds__(256)
void gather_v(){
  int i = blockIdx.x;
  int b = i >> 12;
  int tid = threadIdx.x;
  __shared__ float ws8[8];
  __shared__ int id8[8];
  if (tid < 8){ ws8[tid] = g_t8w[(size_t)i * 8 + tid]; id8[tid] = g_t8i[(size_t)i * 8 + tid]; }
  __syncthreads();
  int d0 = tid * 4;
  float a0 = 0.f, a1 = 0.f, a2 = 0.f, a3 = 0.f;
  #pragma unroll
  for (int rk = 0; rk < 8; rk++){
    int j = id8[rk];
    if (j < 0) continue;
    float wgt = ws8[rk];
    float4 vv = *(const float4*)&g_Vf[((size_t)(b * N_ + j)) * D_ + d0];
    a0 += wgt * vv.x; a1 += wgt * vv.y; a2 += wgt * vv.z; a3 += wgt * vv.w;
  }
  ushort4 o;
  o.x = f2b(a0); o.y = f2b(a1); o.z = f2b(a2); o.w = f2b(a3);
  *(ushort4*)&g_AO[(size_t)i * D_ + d0] = o;
}

// ---------------------------------------------------------------------------
extern "C" void kernel_launch(void* const* d_in, const int* in_sizes, int n_in,
                              void* d_out, int out_size, void* d_ws, size_t ws_size,
                              hipStream_t stream){
  const float* S  = (const float*)d_in[0];
  const float* Wq = (const float*)d_in[1];
  const float* bq = (const float*)d_in[2];
  const float* Wk = (const float*)d_in[3];
  const float* bk = (const float*)d_in[4];
  const float* Wv = (const float*)d_in[5];
  const float* bv = (const float*)d_in[6];
  const float* Wo = (const float*)d_in[7];
  const float* bo = (const float*)d_in[8];
  float* out = (float*)d_out;
  (void)d_ws; (void)ws_size; (void)in_sizes; (void)n_in; (void)out_size;

  transpose2<<<dim3(32, 32, 2), dim3(32, 8), 0, stream>>>(Wv, Wo);
  qk_f64_gemm<<<dim3(256, 8, 2), 256, 0, stream>>>(S, Wq, bq, Wk, bk);
  gemm_bf16<<<dim3(128, 8), 256, 0, stream>>>(S, bv, nullptr, 0);
  scores_gemm<<<dim3(32, 32, 4), 256, 0, stream>>>();
  row_topk<<<dim3(M_ / 4), 256, 0, stream>>>();
  rescore_top8<<<dim3(M_), 256, 0, stream>>>();
  gather_v<<<dim3(M_), 256, 0, stream>>>();
  gemm_bf16<<<dim3(128, 8), 256, 0, stream>>>(nullptr, bo, out, 1);
}

// Round 6
// 2677.836 us; speedup vs baseline: 1.3620x; 1.0483x over previous
//
#include <hip/hip_runtime.h>
#include <cstdint>
#include <cstddef>

#define B_ 4
#define N_ 4096
#define D_ 1024
#define CAND 16
#define M_ (B_*N_)
#define MD_ ((size_t)M_ * D_)

typedef __attribute__((ext_vector_type(8))) short short8;
typedef __attribute__((ext_vector_type(4))) float floatx4;

// ---------------------------------------------------------------------------
// Static device-global scratch (~677 MiB). d_ws proved tiny in rounds 1-2.
// Every buffer fully overwritten before first read on every call.
// ---------------------------------------------------------------------------
__device__ __align__(16) double         g_Qd[MD_];            // 128 MiB exact q
__device__ __align__(16) double         g_Kd[MD_];            // 128 MiB exact k
__device__ __align__(16) unsigned short g_Qb[MD_];            // 32 MiB bf16 q
__device__ __align__(16) unsigned short g_Kb[MD_];            // 32 MiB bf16 k
__device__ __align__(16) float          g_Vf[MD_];            // 64 MiB fp32 v
__device__ __align__(16) unsigned short g_AO[MD_];            // 32 MiB bf16 attn-out
__device__ __align__(16) unsigned short g_WvT[(size_t)D_ * D_];  // 2 MiB bf16
__device__ __align__(16) unsigned short g_WoT[(size_t)D_ * D_];  // 2 MiB bf16
__device__ __align__(16) float          g_S[(size_t)B_ * N_ * N_]; // 256 MiB scores
__device__ __align__(16) int            g_cand[(size_t)M_ * CAND];
__device__ __align__(16) int            g_t8i[(size_t)M_ * 8];
__device__ __align__(16) float          g_t8w[(size_t)M_ * 8];

__device__ __forceinline__ float b2f(unsigned short u){
  return __uint_as_float(((unsigned int)u) << 16);
}
__device__ __forceinline__ unsigned short f2b(float f){
  unsigned int b = __float_as_uint(f);
  b += 0x7fffu + ((b >> 16) & 1u);   // RNE
  return (unsigned short)(b >> 16);
}

// ---------------------------------------------------------------------------
// Transpose Wv, Wo (fp32 [k][n] -> bf16 [n][k]) for B^T-layout bf16 GEMM
// ---------------------------------------------------------------------------
__global__ __launch_bounds__(256)
void transpose2(const float* __restrict__ Wv, const float* __restrict__ Wo){
  __shared__ float tile[32][33];
  const float* src = blockIdx.z ? Wo : Wv;
  unsigned short* dst = blockIdx.z ? g_WoT : g_WvT;
  int tx = threadIdx.x, ty = threadIdx.y;
  int n0 = blockIdx.x * 32, k0 = blockIdx.y * 32;
  for (int r = ty; r < 32; r += 8) tile[r][tx] = src[(size_t)(k0 + r) * D_ + n0 + tx];
  __syncthreads();
  for (int r = ty; r < 32; r += 8) dst[(size_t)(n0 + r) * D_ + k0 + tx] = f2b(tile[tx][r]);
}

// ---------------------------------------------------------------------------
// Exact projection GEMM: out = X @ W + bias (X,W fp32; fp64 accumulate).
// Round-6 rewrite:
//  - swizzled LDS layout phys(n)=n+(n>>4)*2: staging writes are ds_write_b128
//    at bandwidth-floor bank spread (round-5 had 32-way conflicts, 1.5e8 cyc)
//  - fp32->fp64 cvt at stage time (4/thread/k0) not in the kk loop
//  - contiguous 4x8 thread tile -> 6 ds_read_b128 per kk (broadcast, <=2-way)
//  - register prefetch of k0+1 global loads issued before compute
// Block 256 thr, tile 64(M) x 128(N), BK=16.
// blockIdx.z==0 -> Q buffers, ==1 -> K buffers. Emits fp64 + bf16 copies.
// ---------------------------------------------------------------------------
#define ARO 72    // Ad row stride (doubles): 64 + 6 pad, rounded to 72
#define BRO 146   // Bd row stride (doubles): 128 + 14 pad, rounded to 146

__global__ __launch_bounds__(256)
void qk_f64_gemm(const float* __restrict__ X,
                 const float* __restrict__ Wq, const float* __restrict__ bq,
                 const float* __restrict__ Wk, const float* __restrict__ bk){
  int which = blockIdx.z;
  const float* __restrict__ W = which ? Wk : Wq;
  const float* __restrict__ bias = which ? bk : bq;
  double* __restrict__ outd = which ? g_Kd : g_Qd;
  unsigned short* __restrict__ outb = which ? g_Kb : g_Qb;

  __shared__ double __align__(16) Ad[16 * ARO];   // [k][phys(m)]  9216 B
  __shared__ double __align__(16) Bd[16 * BRO];   // [k][phys(n)] 18688 B

  int tid = threadIdx.x;
  int tx = tid & 15, ty = tid >> 4;
  size_t m0 = (size_t)blockIdx.x * 64;
  int n0 = blockIdx.y * 128;

  // staging assignments
  int ar = tid >> 2, ac4 = (tid & 3) * 4;        // A: 64 rows x 16 cols, float4/thr
  int pa_m = ar + ((ar >> 4) << 1);              // phys(m) for writes
  int br = tid >> 4, bn4 = (tid & 15) * 4;       // B: 16 rows x 128 cols, 2 float4/thr
  int pb_n = bn4 + ((bn4 >> 4) << 1);            // phys(n) for first group
  // compute-phase read offsets
  int ty4 = ty * 4;
  int pty = ty4 + ((ty4 >> 4) << 1);
  int tx8 = tx * 8;
  int ptx = tx8 + ((tx8 >> 4) << 1);

  double acc[4][8];
  #pragma unroll
  for (int u = 0; u < 4; u++)
    #pragma unroll
    for (int v = 0; v < 8; v++) acc[u][v] = 0.0;

  // prefetch k0 = 0
  float4 xa = *(const float4*)&X[(m0 + ar) * D_ + ac4];
  float4 wa = *(const float4*)&W[(size_t)br * D_ + n0 + bn4];
  float4 wb = *(const float4*)&W[(size_t)br * D_ + n0 + bn4 + 64];

  for (int k0 = 0; k0 < D_; k0 += 16){
    // stage current tile (cvt to fp64 here, amortized over 16 kk reads)
    Ad[(ac4 + 0) * ARO + pa_m] = (double)xa.x;
    Ad[(ac4 + 1) * ARO + pa_m] = (double)xa.y;
    Ad[(ac4 + 2) * ARO + pa_m] = (double)xa.z;
    Ad[(ac4 + 3) * ARO + pa_m] = (double)xa.w;
    double* bw = &Bd[br * BRO + pb_n];
    { double2 t0; t0.x = (double)wa.x; t0.y = (double)wa.y; *(double2*)(bw + 0) = t0;
      double2 t1; t1.x = (double)wa.z; t1.y = (double)wa.w; *(double2*)(bw + 2) = t1;
      double2 t2; t2.x = (double)wb.x; t2.y = (double)wb.y; *(double2*)(bw + 72) = t2;
      double2 t3; t3.x = (double)wb.z; t3.y = (double)wb.w; *(double2*)(bw + 74) = t3; }
    __syncthreads();
    // prefetch next tile (latency hidden behind the 512-FMA compute phase)
    if (k0 + 16 < D_){
      xa = *(const float4*)&X[(m0 + ar) * D_ + k0 + 16 + ac4];
      wa = *(const float4*)&W[(size_t)(k0 + 16 + br) * D_ + n0 + bn4];
      wb = *(const float4*)&W[(size_t)(k0 + 16 + br) * D_ + n0 + bn4 + 64];
    }
    #pragma unroll
    for (int kk = 0; kk < 16; kk++){
      const double* ap = &Ad[kk * ARO + pty];
      const double* bp = &Bd[kk * BRO + ptx];
      double2 a01 = *(const double2*)(ap + 0);
      double2 a23 = *(const double2*)(ap + 2);
      double2 b01 = *(const double2*)(bp + 0);
      double2 b23 = *(const double2*)(bp + 2);
      double2 b45 = *(const double2*)(bp + 4);
      double2 b67 = *(const double2*)(bp + 6);
      double a_[4] = {a01.x, a01.y, a23.x, a23.y};
      double b_[8] = {b01.x, b01.y, b23.x, b23.y, b45.x, b45.y, b67.x, b67.y};
      #pragma unroll
      for (int u = 0; u < 4; u++)
        #pragma unroll
        for (int v = 0; v < 8; v++) acc[u][v] = fma(a_[u], b_[v], acc[u][v]);
    }
    __syncthreads();
  }
  #pragma unroll
  for (int u = 0; u < 4; u++){
    size_t i = m0 + ty4 + u;
    #pragma unroll
    for (int v = 0; v < 8; v++){
      int j = n0 + tx8 + v;
      double val = acc[u][v] + (double)bias[j];
      outd[i * D_ + j] = val;
      outb[i * D_ + j] = f2b((float)val);
    }
  }
}

// ---------------------------------------------------------------------------
// bf16 MFMA GEMM (m93-style): C = A @ Bt^T + bias, fp32 out.
// Block 256 thr = 4 waves (2x2), tile 128x128, wave 64x64, 16x16x32 MFMA.
// sel==0: A=Af32 (fp32 -> bf16 on stage), Bt=g_WvT, C=g_Vf   (V projection)
// sel==1: A=g_AO (bf16),                  Bt=g_WoT, C=Cout   (O projection)
// ---------------------------------------------------------------------------
__global__ __launch_bounds__(256)
void gemm_bf16(const float* __restrict__ Af32, const float* __restrict__ bias,
               float* __restrict__ Cout, int sel){
  const unsigned short* Bt = sel ? g_WoT : g_WvT;
  float* C = sel ? Cout : g_Vf;
  __shared__ unsigned short __align__(16) As[128 * 32];
  __shared__ unsigned short __align__(16) Bs[128 * 32];
  int tid = threadIdx.x;
  size_t m0 = (size_t)blockIdx.x * 128;
  int n0 = blockIdx.y * 128;
  int l = tid & 63, wid = tid >> 6;
  int wm = (wid >> 1) * 64, wn = (wid & 1) * 64;
  int quad = l >> 4, lr = l & 15;
  int srow = tid >> 2, scol = (tid & 3) * 8;
  floatx4 acc[4][4];
  #pragma unroll
  for (int i = 0; i < 4; i++)
    #pragma unroll
    for (int j = 0; j < 4; j++) acc[i][j] = (floatx4)0.0f;

  for (int k0 = 0; k0 < D_; k0 += 32){
    #pragma unroll
    for (int it = 0; it < 2; it++){
      int r = srow + it * 64;
      if (sel == 0){
        float4 f0 = *(const float4*)&Af32[(m0 + r) * D_ + k0 + scol];
        float4 f1 = *(const float4*)&Af32[(m0 + r) * D_ + k0 + scol + 4];
        ushort4 u0, u1;
        u0.x = f2b(f0.x); u0.y = f2b(f0.y); u0.z = f2b(f0.z); u0.w = f2b(f0.w);
        u1.x = f2b(f1.x); u1.y = f2b(f1.y); u1.z = f2b(f1.z); u1.w = f2b(f1.w);
        *(ushort4*)&As[r * 32 + scol] = u0;
        *(ushort4*)&As[r * 32 + scol + 4] = u1;
      } else {
        *(uint4*)&As[r * 32 + scol] = *(const uint4*)&g_AO[(m0 + r) * D_ + k0 + scol];
      }
      *(uint4*)&Bs[r * 32 + scol] = *(const uint4*)&Bt[(size_t)(n0 + r) * D_ + k0 + scol];
    }
    __syncthreads();
    short8 af[4], bf[4];
    #pragma unroll
    for (int i = 0; i < 4; i++) af[i] = *(short8*)&As[(wm + i * 16 + lr) * 32 + quad * 8];
    #pragma unroll
    for (int j = 0; j < 4; j++) bf[j] = *(short8*)&Bs[(wn + j * 16 + lr) * 32 + quad * 8];
    #pragma unroll
    for (int i = 0; i < 4; i++)
      #pragma unroll
      for (int j = 0; j < 4; j++)
        acc[i][j] = __builtin_amdgcn_mfma_f32_16x16x32_bf16(af[i], bf[j], acc[i][j], 0, 0, 0);
    __syncthreads();
  }
  // C/D layout (m89-verified): col = lane&15, row = quad*4 + reg
  #pragma unroll
  for (int i = 0; i < 4; i++)
    #pragma unroll
    for (int j = 0; j < 4; j++)
      #pragma unroll
      for (int rg = 0; rg < 4; rg++){
        size_t row = m0 + wm + i * 16 + quad * 4 + rg;
        int col = n0 + wn + j * 16 + lr;
        C[row * D_ + col] = acc[i][j][rg] + bias[col];
      }
}

// ---------------------------------------------------------------------------
// Causal score tiles: S[b][i][j] = (q_i . k_j)/32, fp32, 128x128 tiles.
// Grid (32, 32, 4) = (jt, it, b); jt > it exits early. Diagonal masks j > i.
// ---------------------------------------------------------------------------
__global__ __launch_bounds__(256)
void scores_gemm(){
  int jt = blockIdx.x, it = blockIdx.y, b = blockIdx.z;
  if (jt > it) return;
  __shared__ unsigned short __align__(16) As[128 * 32];
  __shared__ unsigned short __align__(16) Bs[128 * 32];
  int tid = threadIdx.x;
  size_t am0 = (size_t)b * N_ + it * 128;   // Q rows (global)
  size_t bn0 = (size_t)b * N_ + jt * 128;   // K rows (global)
  int l = tid & 63, wid = tid >> 6;
  int wm = (wid >> 1) * 64, wn = (wid & 1) * 64;
  int quad = l >> 4, lr = l & 15;
  int srow = tid >> 2, scol = (tid & 3) * 8;
  floatx4 acc[4][4];
  #pragma unroll
  for (int i = 0; i < 4; i++)
    #pragma unroll
    for (int j = 0; j < 4; j++) acc[i][j] = (floatx4)0.0f;

  for (int k0 = 0; k0 < D_; k0 += 32){
    #pragma unroll
    for (int it2 = 0; it2 < 2; it2++){
      int r = srow + it2 * 64;
      *(uint4*)&As[r * 32 + scol] = *(const uint4*)&g_Qb[(am0 + r) * D_ + k0 + scol];
      *(uint4*)&Bs[r * 32 + scol] = *(const uint4*)&g_Kb[(bn0 + r) * D_ + k0 + scol];
    }
    __syncthreads();
    short8 af[4], bf[4];
    #pragma unroll
    for (int i = 0; i < 4; i++) af[i] = *(short8*)&As[(wm + i * 16 + lr) * 32 + quad * 8];
    #pragma unroll
    for (int j = 0; j < 4; j++) bf[j] = *(short8*)&Bs[(wn + j * 16 + lr) * 32 + quad * 8];
    #pragma unroll
    for (int i = 0; i < 4; i++)
      #pragma unroll
      for (int j = 0; j < 4; j++)
        acc[i][j] = __builtin_amdgcn_mfma_f32_16x16x32_bf16(af[i], bf[j], acc[i][j], 0, 0, 0);
    __syncthreads();
  }
  #pragma unroll
  for (int i = 0; i < 4; i++)
    #pragma unroll
    for (int j = 0; j < 4; j++)
      #pragma unroll
      for (int rg = 0; rg < 4; rg++){
        int row = it * 128 + wm + i * 16 + quad * 4 + rg;   // in-batch
        int col = jt * 128 + wn + j * 16 + lr;
        float v = acc[i][j][rg] * 0.03125f;
        if (col > row) v = -3.0e38f;
        g_S[((size_t)b * N_ + row) * N_ + col] = v;
      }
}

// ---------------------------------------------------------------------------
// Per-row top-16 of causal scores. One wave per row (4 rows/block).
// ---------------------------------------------------------------------------
__global__ __launch_bounds__(256)
void row_topk(){
  __shared__ float lv[CAND * 256];   // [u][wave*64+lane]
  __shared__ int   li[CAND * 256];
  int w = threadIdx.x >> 6, l = threadIdx.x & 63;
  int g = threadIdx.x;
  int i = blockIdx.x * 4 + w;               // global row
  int irow = i & (N_ - 1);                  // in-batch row
  const float* Srow = &g_S[(size_t)i * N_];
  #pragma unroll
  for (int u = 0; u < CAND; u++){ lv[u * 256 + g] = -3.0e38f; li[u * 256 + g] = -1; }
  float vmin = -3.0e38f; int pmin = 0;
  for (int j = l; j <= irow; j += 64){
    float v = Srow[j];
    if (v > vmin){
      lv[pmin * 256 + g] = v; li[pmin * 256 + g] = j;
      float m = lv[g]; int p = 0;
      #pragma unroll
      for (int u = 1; u < CAND; u++){ float x = lv[u * 256 + g]; if (x < m){ m = x; p = u; } }
      vmin = m; pmin = p;
    }
  }
  float mv = lv[g]; int mp = 0;
  #pragma unroll
  for (int u = 1; u < CAND; u++){ float x = lv[u * 256 + g]; if (x > mv){ mv = x; mp = u; } }
  int mj = li[mp * 256 + g];
  for (int rd = 0; rd < CAND; rd++){
    float bv = mv; int bj = mj; int bl = l;
    #pragma unroll
    for (int off = 32; off >= 1; off >>= 1){
      float ov = __shfl_xor(bv, off);
      int oj = __shfl_xor(bj, off);
      int ol = __shfl_xor(bl, off);
      if (ov > bv || (ov == bv && ol < bl)){ bv = ov; bj = oj; bl = ol; }
    }
    bool valid = (bv > -2.9e38f);
    if (l == 0) g_cand[(size_t)i * CAND + rd] = valid ? bj : -1;
    if (valid && bl == l){
      lv[mp * 256 + g] = -3.0e38f;
      mv = lv[g]; mp = 0;
      #pragma unroll
      for (int u = 1; u < CAND; u++){ float x = lv[u * 256 + g]; if (x > mv){ mv = x; mp = u; } }
      mj = li[mp * 256 + g];
    }
  }
}

// ---------------------------------------------------------------------------
// fp64 rescore of 16 candidates/row -> exact top-8 + softmax weights.
// ---------------------------------------------------------------------------
__global__ __launch_bounds__(256)
void rescore_top8(){
  int i = blockIdx.x;
  int b = i >> 12;
  int tid = threadIdx.x, l = tid & 63, w = tid >> 6;
  __shared__ double cs[CAND];
  __shared__ int cid[CAND];
  if (tid < CAND) cid[tid] = g_cand[(size_t)i * CAND + tid];
  __syncthreads();
  double q[16];
  #pragma unroll
  for (int u = 0; u < 16; u++) q[u] = g_Qd[(size_t)i * D_ + l + 64 * u];
  for (int c = w * 4; c < w * 4 + 4; c++){
    int j = cid[c];
    double s = 0.0;
    if (j >= 0){
      size_t ko = ((size_t)(b * N_ + j)) * D_;
      #pragma unroll
      for (int u = 0; u < 16; u++) s = fma(q[u], g_Kd[ko + l + 64 * u], s);
    }
    #pragma unroll
    for (int off = 32; off >= 1; off >>= 1) s += __shfl_down(s, off);
    if (l == 0) cs[c] = (j >= 0) ? s * 0.03125 : -1.0e300;
  }
  __syncthreads();
  if (tid == 0){
    double v8[8]; int i8[8];
    bool used[CAND];
    for (int u = 0; u < CAND; u++) used[u] = false;
    for (int rk = 0; rk < 8; rk++){
      double best = -1.0e300; int bp = -1;
      for (int c = 0; c < CAND; c++)
        if (!used[c] && cid[c] >= 0 && cs[c] > best){ best = cs[c]; bp = c; }
      if (bp >= 0){ used[bp] = true; v8[rk] = best; i8[rk] = cid[bp]; }
      else { v8[rk] = -1.0e300; i8[rk] = -1; }
    }
    if (i8[0] < 0){ i8[0] = i & (N_ - 1); v8[0] = 0.0; }   // never expected
    double mx = v8[0];
    double e[8]; double Z = 0.0;
    for (int rk = 0; rk < 8; rk++){
      e[rk] = (i8[rk] >= 0) ? exp(v8[rk] - mx) : 0.0;
      Z += e[rk];
    }
    for (int rk = 0; rk < 8; rk++){
      g_t8i[(size_t)i * 8 + rk] = i8[rk];
      g_t8w[(size_t)i * 8 + rk] = (float)(e[rk] / Z);
    }
  }
}

// ---------------------------------------------------------------------------
// attn_out[i] = sum_r w_r * v[idx_r]  (fp32 accumulate, bf16 out for O-GEMM)
// ---------------------------------------------------------------------------
__global__ __launch_bounds__(256)
void gather_v(){
  int i = blockIdx.x;
  int b = i >> 12;
  int tid = threadIdx.x;
  __shared__ float ws8[8];
  __shared__ int id8[8];
  if (tid < 8){ ws8[tid] = g_t8w[(size_t)i * 8 + tid]; id8[tid] = g_t8i[(size_t)i * 8 + tid]; }
  __syncthreads();
  int d0 = tid * 4;
  float a0 = 0.f, a1 = 0.f, a2 = 0.f, a3 = 0.f;
  #pragma unroll
  for (int rk = 0; rk < 8; rk++){
    int j = id8[rk];
    if (j < 0) continue;
    float wgt = ws8[rk];
    float4 vv = *(const float4*)&g_Vf[((size_t)(b * N_ + j)) * D_ + d0];
    a0 += wgt * vv.x; a1 += wgt * vv.y; a2 += wgt * vv.z; a3 += wgt * vv.w;
  }
  ushort4 o;
  o.x = f2b(a0); o.y = f2b(a1); o.z = f2b(a2); o.w = f2b(a3);
  *(ushort4*)&g_AO[(size_t)i * D_ + d0] = o;
}

// ---------------------------------------------------------------------------
extern "C" void kernel_launch(void* const* d_in, const int* in_sizes, int n_in,
                              void* d_out, int out_size, void* d_ws, size_t ws_size,
                              hipStream_t stream){
  const float* S  = (const float*)d_in[0];
  const float* Wq = (const float*)d_in[1];
  const float* bq = (const float*)d_in[2];
  const float* Wk = (const float*)d_in[3];
  const float* bk = (const float*)d_in[4];
  const float* Wv = (const float*)d_in[5];
  const float* bv = (const float*)d_in[6];
  const float* Wo = (const float*)d_in[7];
  const float* bo = (const float*)d_in[8];
  float* out = (float*)d_out;
  (void)d_ws; (void)ws_size; (void)in_sizes; (void)n_in; (void)out_size;

  transpose2<<<dim3(32, 32, 2), dim3(32, 8), 0, stream>>>(Wv, Wo);
  qk_f64_gemm<<<dim3(256, 8, 2), 256, 0, stream>>>(S, Wq, bq, Wk, bk);
  gemm_bf16<<<dim3(128, 8), 256, 0, stream>>>(S, bv, nullptr, 0);
  scores_gemm<<<dim3(32, 32, 4), 256, 0, stream>>>();
  row_topk<<<dim3(M_ / 4), 256, 0, stream>>>();
  rescore_top8<<<dim3(M_), 256, 0, stream>>>();
  gather_v<<<dim3(M_), 256, 0, stream>>>();
  gemm_bf16<<<dim3(128, 8), 256, 0, stream>>>(nullptr, bo, out, 1);
}